// Round 10
// baseline (337.065 us; speedup 1.0000x reference)
//
#include <hip/hip_runtime.h>
#include <hip/hip_bf16.h>
#include <hip/hip_cooperative_groups.h>

namespace cg = cooperative_groups;

#define NS 8192
#define NQ 8192
#define NTOT 16384
#define KDIM 1024
#define ED 512
#define NC 64
#define PBLK 64

typedef __attribute__((ext_vector_type(4))) float fx4;
typedef __attribute__((ext_vector_type(4))) int ix4;
typedef __attribute__((ext_vector_type(8))) short sx8;
typedef __attribute__((ext_vector_type(8))) unsigned short ux8;

__device__ __forceinline__ unsigned short f2bf(float f) {
  union { float f; unsigned u; } v; v.f = f;
  unsigned r = v.u + 0x7fffu + ((v.u >> 16) & 1u);   // RNE
  return (unsigned short)(r >> 16);
}
__device__ __forceinline__ float bf2f(unsigned short h) {
  union { unsigned u; float f; } v; v.u = ((unsigned)h) << 16;
  return v.f;
}

// async global->LDS DMA, 16 B per lane. LDS dest = wave-uniform base + lane*16.
__device__ __forceinline__ void async_ld16(const void* g, void* l) {
  __builtin_amdgcn_global_load_lds(
      (const __attribute__((address_space(1))) unsigned int*)g,
      (__attribute__((address_space(3))) unsigned int*)l, 16, 0, 0);
}

// 64 KB LDS union (same footprint as the proven R8 GEMM kernel).
union SM {
  struct { unsigned short A[2][128 * 8 * 8]; unsigned short B[2][128 * 8 * 8]; } g;  // 64 KB
  float wtile[32][33];     // prep
  float proto[NC * 128];   // 32 KB (proto_partial)
};

// ===========================================================================
// Fused cooperative kernel: 256 blocks (1/CU — always co-residency-admissible)
// x 256 threads, 5 phases / 4 grid syncs. Phase logic = R8 kernels, persistent.
// ===========================================================================
__global__ __launch_bounds__(256, 1) void k_fused(
    const float* __restrict__ W, const float* __restrict__ Xs,
    const float* __restrict__ Xq, const int* __restrict__ labels,
    unsigned short* __restrict__ Wt, unsigned short* __restrict__ Xbf,
    unsigned short* __restrict__ emb, float* __restrict__ rowssq,
    float* __restrict__ Ppart, unsigned short* __restrict__ Pbf,
    float* __restrict__ out) {
  __shared__ SM sm;
  cg::grid_group grid = cg::this_grid();

  int lid = blockIdx.x;   // 0..255
  int t = threadIdx.x;
  int lane = t & 63, w = t >> 6;

  // -------- phase 0: X fp32->bf16 (64 rows/block), W->Wt (2 tiles), ssq=0 ---
  {
    const float* Xsrc = (lid < 128) ? Xs : Xq;
    size_t src0 = (size_t)(lid & 127) * 65536;   // 64 rows
    size_t dst0 = (size_t)lid * 65536;
#pragma unroll
    for (int c = 0; c < 32; ++c) {
      size_t e = src0 + (size_t)c * 2048 + (size_t)t * 8;
      fx4 v0 = *(const fx4*)&Xsrc[e];
      fx4 v1 = *(const fx4*)&Xsrc[e + 4];
      ux8 b;
      b[0] = f2bf(v0.x); b[1] = f2bf(v0.y); b[2] = f2bf(v0.z); b[3] = f2bf(v0.w);
      b[4] = f2bf(v1.x); b[5] = f2bf(v1.y); b[6] = f2bf(v1.z); b[7] = f2bf(v1.w);
      *(ux8*)&Xbf[dst0 + (size_t)c * 2048 + (size_t)t * 8] = b;
    }
    int tx = t & 31, ty = t >> 5;
    for (int tt = lid; tt < 512; tt += 256) {    // W: 2 tiles of 32x32
      int k0 = (tt & 31) * 32;
      int n0 = (tt >> 5) * 32;
      __syncthreads();
#pragma unroll
      for (int i = ty; i < 32; i += 8)
        sm.wtile[i][tx] = W[(size_t)(k0 + i) * ED + n0 + tx];
      __syncthreads();
#pragma unroll
      for (int i = ty; i < 32; i += 8)
        Wt[(size_t)(n0 + i) * KDIM + k0 + tx] = f2bf(sm.wtile[tx][i]);
    }
    if (t < 64) rowssq[lid * 64 + t] = 0.f;
  }
  grid.sync();

  // -------- phase 1: emb = Xbf @ Wt^T, 128x128 tiles, BK=64, DMA dbuf, x2 ---
  {
    int wm = w >> 1, wn = w & 1;
    int quad = lane >> 4, ml = lane & 15;

    for (int tile = lid; tile < 512; tile += 256) {
      int x = tile & 7;
      int s = tile >> 3;
      int m_blk = x * 16 + (s >> 2);   // 0..127
      int n_blk = s & 3;               // 0..3

      const unsigned short* Xrow = Xbf + (size_t)m_blk * 128 * KDIM;
      const unsigned short* Wrow = Wt + (size_t)n_blk * 128 * KDIM;

      fx4 acc[4][4];
#pragma unroll
      for (int i = 0; i < 4; ++i)
#pragma unroll
        for (int j = 0; j < 4; ++j) acc[i][j] = fx4{0.f, 0.f, 0.f, 0.f};

      auto stage = [&](int kt, int b) {
        int k0 = kt * 64;
#pragma unroll
        for (int c = 0; c < 4; ++c) {
          int ch = t + 256 * c;
          int m = ch >> 3;
          int kq = (ch & 7) ^ (m & 7);
          async_ld16(&Xrow[(size_t)m * KDIM + k0 + kq * 8],
                     &sm.g.A[b][(w * 64 + 256 * c) * 8]);
        }
#pragma unroll
        for (int c = 0; c < 4; ++c) {
          int ch = t + 256 * c;
          int n = ch >> 3;
          int kq = (ch & 7) ^ (n & 7);
          async_ld16(&Wrow[(size_t)n * KDIM + k0 + kq * 8],
                     &sm.g.B[b][(w * 64 + 256 * c) * 8]);
        }
      };

      stage(0, 0);
      for (int kt = 0; kt < 16; ++kt) {
        int b = kt & 1;
        __syncthreads();
        if (kt < 15) stage(kt + 1, b ^ 1);
#pragma unroll
        for (int s2 = 0; s2 < 2; ++s2) {
          int kq = s2 * 4 + quad;
          sx8 af[4], bfr[4];
#pragma unroll
          for (int i = 0; i < 4; ++i) {
            int row = wm * 64 + i * 16 + ml;
            af[i] = *(const sx8*)&sm.g.A[b][(row * 8 + (kq ^ (row & 7))) * 8];
          }
#pragma unroll
          for (int j = 0; j < 4; ++j) {
            int nrow = wn * 64 + j * 16 + ml;
            bfr[j] = *(const sx8*)&sm.g.B[b][(nrow * 8 + (kq ^ (nrow & 7))) * 8];
          }
#pragma unroll
          for (int i = 0; i < 4; ++i)
#pragma unroll
            for (int j = 0; j < 4; ++j)
              acc[i][j] = __builtin_amdgcn_mfma_f32_16x16x32_bf16(af[i], bfr[j], acc[i][j], 0, 0, 0);
        }
      }

      int grow = m_blk * 128 + wm * 64;
      int gcol = n_blk * 128 + wn * 64;
#pragma unroll
      for (int i = 0; i < 4; ++i) {
#pragma unroll
        for (int r = 0; r < 4; ++r) {
          int mrow = grow + i * 16 + quad * 4 + r;
          float p = 0.f;
#pragma unroll
          for (int j = 0; j < 4; ++j) {
            emb[(size_t)mrow * ED + gcol + j * 16 + ml] = f2bf(acc[i][j][r]);
            p += acc[i][j][r] * acc[i][j][r];
          }
#pragma unroll
          for (int off = 1; off < 16; off <<= 1) p += __shfl_xor(p, off, 16);
          if (ml == 0) atomicAdd(&rowssq[mrow], p);
        }
      }
      __syncthreads();   // all buf reads done before next tile's stage(0,0)
    }
  }
  grid.sync();

  // -------- phase 2: per-class partials, 64 chunks x 4 dim-slices(128) ------
  {
    int chunk = lid & 63;            // 128 support rows
    int ds = lid >> 6;               // dims [ds*128, ds*128+128)
#pragma unroll
    for (int i = 0; i < 32; ++i) sm.proto[i * 256 + t] = 0.f;
    __syncthreads();

    int row0 = chunk * 128;
#pragma unroll 4
    for (int r = w; r < 128; r += 4) {
      int row = row0 + r;
      int lbl = labels[row];
      float scale = 1.0f / fmaxf(sqrtf(rowssq[row]), 1e-12f);
      const unsigned short* er = &emb[(size_t)row * ED + ds * 128];
      float v0 = bf2f(er[lane]) * scale;
      float v1 = bf2f(er[lane + 64]) * scale;
      atomicAdd(&sm.proto[lbl * 128 + lane], v0);        // banks: 2-way, free
      atomicAdd(&sm.proto[lbl * 128 + lane + 64], v1);
    }
    __syncthreads();

    float* o = Ppart + (size_t)chunk * NC * ED + ds * 128;
#pragma unroll
    for (int i = 0; i < 32; ++i) {
      int idx = i * 256 + t;
      o[(size_t)(idx >> 7) * ED + (idx & 127)] = sm.proto[idx];
    }
  }
  grid.sync();

  // -------- phase 3: reduce 64 partials -> Pbf (B-fragment layout) ----------
  if (lid < 128) {
    int idx = lid * 256 + t;
    int kq = idx >> 9;
    int n = (idx >> 3) & 63;
    int j = idx & 7;
    int d = kq * 8 + j;
    float s = 0.f;
#pragma unroll 8
    for (int b = 0; b < 64; ++b) s += Ppart[(size_t)b * NC * ED + n * ED + d];
    Pbf[idx] = f2bf(s);
  }
  grid.sync();

  // -------- phase 4: scores + softmax (256 blocks x 2 waves x 16 q) ---------
  if (w < 2) {
    int quad = lane >> 4, ml = lane & 15;
    int qrow0 = lid * 32 + w * 16;
    const unsigned short* embQ = emb + (size_t)NS * ED;
    const float* ssqQ = rowssq + NS;

    fx4 acc[4];
#pragma unroll
    for (int i = 0; i < 4; ++i) acc[i] = fx4{0.f, 0.f, 0.f, 0.f};

#pragma unroll 4
    for (int ki = 0; ki < 16; ++ki) {
      sx8 a = *(const sx8*)&embQ[(size_t)(qrow0 + ml) * ED + ki * 32 + quad * 8];
#pragma unroll
      for (int nt = 0; nt < 4; ++nt) {
        sx8 b = *(const sx8*)&Pbf[((ki * 4 + quad) * 64 + nt * 16 + ml) * 8];
        acc[nt] = __builtin_amdgcn_mfma_f32_16x16x32_bf16(a, b, acc[nt], 0, 0, 0);
      }
    }

#pragma unroll
    for (int r = 0; r < 4; ++r) {
      int qq = qrow0 + quad * 4 + r;
      float scale = 1.0f / fmaxf(sqrtf(ssqQ[qq]), 1e-12f);
      float s[4];
#pragma unroll
      for (int nt = 0; nt < 4; ++nt) s[nt] = acc[nt][r] * scale;
      float m = fmaxf(fmaxf(s[0], s[1]), fmaxf(s[2], s[3]));
#pragma unroll
      for (int off = 1; off < 16; off <<= 1) m = fmaxf(m, __shfl_xor(m, off, 16));
      float e[4], ssum = 0.f;
#pragma unroll
      for (int nt = 0; nt < 4; ++nt) { e[nt] = __expf(s[nt] - m); ssum += e[nt]; }
#pragma unroll
      for (int off = 1; off < 16; off <<= 1) ssum += __shfl_xor(ssum, off, 16);
      float inv = 1.0f / ssum;
#pragma unroll
      for (int nt = 0; nt < 4; ++nt)
        out[(size_t)qq * NC + nt * 16 + ml] = e[nt] * inv;
    }
  }
}

// ===========================================================================
// R8 fallback pipeline (proven 170 us) — used if cooperative launch fails.
// ===========================================================================
__global__ __launch_bounds__(256) void k_prep(
    const float* __restrict__ W, const float* __restrict__ Xs,
    const float* __restrict__ Xq, unsigned short* __restrict__ Wt,
    unsigned short* __restrict__ Xbf, float* __restrict__ rowssq) {
  __shared__ float tile[32][33];
  int bid = blockIdx.x;
  int t = threadIdx.x;
  if (bid < 512) {
    int k0 = (bid & 31) * 32;
    int n0 = (bid >> 5) * 32;
    int tx = t & 31, ty = t >> 5;
#pragma unroll
    for (int i = ty; i < 32; i += 8)
      tile[i][tx] = W[(size_t)(k0 + i) * ED + n0 + tx];
    __syncthreads();
#pragma unroll
    for (int i = ty; i < 32; i += 8)
      Wt[(size_t)(n0 + i) * KDIM + k0 + tx] = f2bf(tile[tx][i]);
  } else {
    int cb = bid - 512;
    const float* X = (cb < 1024) ? Xs : Xq;
    size_t src0 = (size_t)(cb & 1023) * 8192;
    size_t dst0 = (size_t)cb * 8192;
#pragma unroll
    for (int c = 0; c < 4; ++c) {
      size_t e = src0 + (size_t)c * 2048 + (size_t)t * 8;
      fx4 v0 = *(const fx4*)&X[e];
      fx4 v1 = *(const fx4*)&X[e + 4];
      ux8 b;
      b[0] = f2bf(v0.x); b[1] = f2bf(v0.y); b[2] = f2bf(v0.z); b[3] = f2bf(v0.w);
      b[4] = f2bf(v1.x); b[5] = f2bf(v1.y); b[6] = f2bf(v1.z); b[7] = f2bf(v1.w);
      *(ux8*)&Xbf[dst0 + (size_t)c * 2048 + (size_t)t * 8] = b;
    }
    if (cb < 8) {
#pragma unroll
      for (int i = t; i < 2048; i += 256) rowssq[cb * 2048 + i] = 0.f;
    }
  }
}

__global__ __launch_bounds__(256) void k_gemm_embed(
    const unsigned short* __restrict__ Xbf, const unsigned short* __restrict__ Wt,
    unsigned short* __restrict__ emb, float* __restrict__ rowssq) {
  __shared__ unsigned short Ash[2][128 * 8 * 8];
  __shared__ unsigned short Bsh[2][128 * 8 * 8];

  int lid = blockIdx.x;
  int x = lid & 7;
  int s = lid >> 3;
  int m_blk = x * 16 + (s >> 2);
  int n_blk = s & 3;

  const unsigned short* Xrow = Xbf + (size_t)m_blk * 128 * KDIM;
  const unsigned short* Wrow = Wt + (size_t)n_blk * 128 * KDIM;

  int t = threadIdx.x;
  int lane = t & 63, w = t >> 6;
  int wm = w >> 1, wn = w & 1;
  int quad = lane >> 4, ml = lane & 15;

  fx4 acc[4][4];
#pragma unroll
  for (int i = 0; i < 4; ++i)
#pragma unroll
    for (int j = 0; j < 4; ++j) acc[i][j] = fx4{0.f, 0.f, 0.f, 0.f};

  auto stage = [&](int kt, int b) {
    int k0 = kt * 64;
#pragma unroll
    for (int c = 0; c < 4; ++c) {
      int ch = t + 256 * c;
      int m = ch >> 3;
      int kq = (ch & 7) ^ (m & 7);
      async_ld16(&Xrow[(size_t)m * KDIM + k0 + kq * 8],
                 &Ash[b][(w * 64 + 256 * c) * 8]);
    }
#pragma unroll
    for (int c = 0; c < 4; ++c) {
      int ch = t + 256 * c;
      int n = ch >> 3;
      int kq = (ch & 7) ^ (n & 7);
      async_ld16(&Wrow[(size_t)n * KDIM + k0 + kq * 8],
                 &Bsh[b][(w * 64 + 256 * c) * 8]);
    }
  };

  stage(0, 0);
  for (int kt = 0; kt < 16; ++kt) {
    int b = kt & 1;
    __syncthreads();
    if (kt < 15) stage(kt + 1, b ^ 1);
#pragma unroll
    for (int s2 = 0; s2 < 2; ++s2) {
      int kq = s2 * 4 + quad;
      sx8 af[4], bfr[4];
#pragma unroll
      for (int i = 0; i < 4; ++i) {
        int row = wm * 64 + i * 16 + ml;
        af[i] = *(const sx8*)&Ash[b][(row * 8 + (kq ^ (row & 7))) * 8];
      }
#pragma unroll
      for (int j = 0; j < 4; ++j) {
        int nrow = wn * 64 + j * 16 + ml;
        bfr[j] = *(const sx8*)&Bsh[b][(nrow * 8 + (kq ^ (nrow & 7))) * 8];
      }
#pragma unroll
      for (int i = 0; i < 4; ++i)
#pragma unroll
        for (int j = 0; j < 4; ++j)
          acc[i][j] = __builtin_amdgcn_mfma_f32_16x16x32_bf16(af[i], bfr[j], acc[i][j], 0, 0, 0);
    }
  }

  int grow = m_blk * 128 + wm * 64;
  int gcol = n_blk * 128 + wn * 64;
#pragma unroll
  for (int i = 0; i < 4; ++i) {
#pragma unroll
    for (int r = 0; r < 4; ++r) {
      int mrow = grow + i * 16 + quad * 4 + r;
      float p = 0.f;
#pragma unroll
      for (int j = 0; j < 4; ++j) {
        emb[(size_t)mrow * ED + gcol + j * 16 + ml] = f2bf(acc[i][j][r]);
        p += acc[i][j][r] * acc[i][j][r];
      }
#pragma unroll
      for (int off = 1; off < 16; off <<= 1) p += __shfl_xor(p, off, 16);
      if (ml == 0) atomicAdd(&rowssq[mrow], p);
    }
  }
}

__global__ __launch_bounds__(256) void k_proto_partial(
    const unsigned short* __restrict__ embS, const float* __restrict__ rowssq,
    const int* __restrict__ labels, float* __restrict__ Ppart) {
  __shared__ float Pl[NC * 64];
  int t = threadIdx.x;
#pragma unroll
  for (int i = 0; i < 16; ++i) Pl[i * 256 + t] = 0.f;
  __syncthreads();

  int w = t >> 6, lane = t & 63;
  int ds = blockIdx.y;
  int row0 = blockIdx.x * (NS / PBLK);
#pragma unroll 4
  for (int r = w; r < NS / PBLK; r += 4) {
    int row = row0 + r;
    int lbl = labels[row];
    float scale = 1.0f / fmaxf(sqrtf(rowssq[row]), 1e-12f);
    float v = bf2f(embS[(size_t)row * ED + ds * 64 + lane]) * scale;
    atomicAdd(&Pl[lbl * 64 + lane], v);
  }
  __syncthreads();

  float* o = Ppart + (size_t)blockIdx.x * NC * ED + ds * 64;
#pragma unroll
  for (int i = 0; i < 16; ++i) {
    int idx = i * 256 + t;
    o[(size_t)(idx >> 6) * ED + (idx & 63)] = Pl[idx];
  }
}

__global__ __launch_bounds__(256) void k_proto_reduce(
    const float* __restrict__ Ppart, unsigned short* __restrict__ Pbf) {
  int idx = blockIdx.x * 256 + threadIdx.x;
  int kq = idx >> 9;
  int n = (idx >> 3) & 63;
  int j = idx & 7;
  int d = kq * 8 + j;
  float s = 0.f;
#pragma unroll 8
  for (int b = 0; b < PBLK; ++b) s += Ppart[(size_t)b * NC * ED + n * ED + d];
  Pbf[idx] = f2bf(s);
}

__global__ __launch_bounds__(64) void k_scores(
    const unsigned short* __restrict__ embQ, const float* __restrict__ ssqQ,
    const unsigned short* __restrict__ Pbf, float* __restrict__ out) {
  int lane = threadIdx.x;
  int quad = lane >> 4, ml = lane & 15;
  int qrow0 = blockIdx.x * 16;

  fx4 acc[4];
#pragma unroll
  for (int i = 0; i < 4; ++i) acc[i] = fx4{0.f, 0.f, 0.f, 0.f};

#pragma unroll 4
  for (int ki = 0; ki < 16; ++ki) {
    sx8 a = *(const sx8*)&embQ[(size_t)(qrow0 + ml) * ED + ki * 32 + quad * 8];
#pragma unroll
    for (int nt = 0; nt < 4; ++nt) {
      sx8 b = *(const sx8*)&Pbf[((ki * 4 + quad) * 64 + nt * 16 + ml) * 8];
      acc[nt] = __builtin_amdgcn_mfma_f32_16x16x32_bf16(a, b, acc[nt], 0, 0, 0);
    }
  }

#pragma unroll
  for (int r = 0; r < 4; ++r) {
    int qq = qrow0 + quad * 4 + r;
    float scale = 1.0f / fmaxf(sqrtf(ssqQ[qq]), 1e-12f);
    float s[4];
#pragma unroll
    for (int nt = 0; nt < 4; ++nt) s[nt] = acc[nt][r] * scale;
    float m = fmaxf(fmaxf(s[0], s[1]), fmaxf(s[2], s[3]));
#pragma unroll
    for (int off = 1; off < 16; off <<= 1) m = fmaxf(m, __shfl_xor(m, off, 16));
    float e[4], ssum = 0.f;
#pragma unroll
    for (int nt = 0; nt < 4; ++nt) { e[nt] = __expf(s[nt] - m); ssum += e[nt]; }
#pragma unroll
    for (int off = 1; off < 16; off <<= 1) ssum += __shfl_xor(ssum, off, 16);
    float inv = 1.0f / ssum;
#pragma unroll
    for (int nt = 0; nt < 4; ++nt)
      out[(size_t)qq * NC + nt * 16 + ml] = e[nt] * inv;
  }
}

// ---------------------------------------------------------------------------
extern "C" void kernel_launch(void* const* d_in, const int* in_sizes, int n_in,
                              void* d_out, int out_size, void* d_ws, size_t ws_size,
                              hipStream_t stream) {
  const float* Xs     = (const float*)d_in[0];
  const int*   labels = (const int*)d_in[1];
  const float* Xq     = (const float*)d_in[2];
  const float* W      = (const float*)d_in[3];
  float* out = (float*)d_out;

  char* ws = (char*)d_ws;
  size_t off = 0;
  unsigned short* Wt  = (unsigned short*)(ws + off); off += (size_t)ED * KDIM * 2;
  unsigned short* Xbf = (unsigned short*)(ws + off); off += (size_t)NTOT * KDIM * 2;
  unsigned short* emb = (unsigned short*)(ws + off); off += (size_t)NTOT * ED * 2;
  float* rowssq = (float*)(ws + off); off += (size_t)NTOT * 4;
  float* Ppart  = (float*)(ws + off); off += (size_t)PBLK * NC * ED * 4;
  unsigned short* Pbf = (unsigned short*)(ws + off); off += (size_t)NC * ED * 2;

  void* args[] = {(void*)&W, (void*)&Xs, (void*)&Xq, (void*)&labels,
                  (void*)&Wt, (void*)&Xbf, (void*)&emb, (void*)&rowssq,
                  (void*)&Ppart, (void*)&Pbf, (void*)&out};
  hipError_t err = hipLaunchCooperativeKernel((const void*)k_fused, dim3(256),
                                              dim3(256), args, 0, stream);
  if (err != hipSuccess) {
    (void)hipGetLastError();  // clear sticky error, take the proven R8 path
    k_prep<<<2560, 256, 0, stream>>>(W, Xs, Xq, Wt, Xbf, rowssq);
    k_gemm_embed<<<512, 256, 0, stream>>>(Xbf, Wt, emb, rowssq);
    k_proto_partial<<<dim3(PBLK, 8), 256, 0, stream>>>(emb, rowssq, labels, Ppart);
    k_proto_reduce<<<NC * ED / 256, 256, 0, stream>>>(Ppart, Pbf);
    k_scores<<<NQ / 16, 64, 0, stream>>>(emb + (size_t)NS * ED, rowssq + NS, Pbf, out);
  }
}

// Round 11
// 244.458 us; speedup vs baseline: 1.3788x; 1.3788x over previous
//
#include <hip/hip_runtime.h>
#include <hip/hip_bf16.h>
#include <hip/hip_cooperative_groups.h>

namespace cg = cooperative_groups;

#define NS 8192
#define NQ 8192
#define NTOT 16384
#define KDIM 1024
#define ED 512
#define NC 64
#define PBLK 64

typedef __attribute__((ext_vector_type(4))) float fx4;
typedef __attribute__((ext_vector_type(4))) int ix4;
typedef __attribute__((ext_vector_type(8))) short sx8;
typedef __attribute__((ext_vector_type(8))) unsigned short ux8;

__device__ __forceinline__ unsigned short f2bf(float f) {
  union { float f; unsigned u; } v; v.f = f;
  unsigned r = v.u + 0x7fffu + ((v.u >> 16) & 1u);   // RNE
  return (unsigned short)(r >> 16);
}
__device__ __forceinline__ float bf2f(unsigned short h) {
  union { unsigned u; float f; } v; v.u = ((unsigned)h) << 16;
  return v.f;
}

// async global->LDS DMA, 16 B per lane. LDS dest = wave-uniform base + lane*16.
__device__ __forceinline__ void async_ld16(const void* g, void* l) {
  __builtin_amdgcn_global_load_lds(
      (const __attribute__((address_space(1))) unsigned int*)g,
      (__attribute__((address_space(3))) unsigned int*)l, 16, 0, 0);
}

// ---------------------------------------------------------------------------
// K0 (R8, proven): blocks [0,512): W -> Wt bf16 (B^T). [512,2560): X -> bf16;
// first 8 convert blocks zero rowssq.
// ---------------------------------------------------------------------------
__global__ __launch_bounds__(256) void k_prep(
    const float* __restrict__ W, const float* __restrict__ Xs,
    const float* __restrict__ Xq, unsigned short* __restrict__ Wt,
    unsigned short* __restrict__ Xbf, float* __restrict__ rowssq) {
  __shared__ float tile[32][33];
  int bid = blockIdx.x;
  int t = threadIdx.x;
  if (bid < 512) {
    int k0 = (bid & 31) * 32;
    int n0 = (bid >> 5) * 32;
    int tx = t & 31, ty = t >> 5;
#pragma unroll
    for (int i = ty; i < 32; i += 8)
      tile[i][tx] = W[(size_t)(k0 + i) * ED + n0 + tx];
    __syncthreads();
#pragma unroll
    for (int i = ty; i < 32; i += 8)
      Wt[(size_t)(n0 + i) * KDIM + k0 + tx] = f2bf(tile[tx][i]);
  } else {
    int cb = bid - 512;
    const float* X = (cb < 1024) ? Xs : Xq;
    size_t src0 = (size_t)(cb & 1023) * 8192;
    size_t dst0 = (size_t)cb * 8192;
#pragma unroll
    for (int c = 0; c < 4; ++c) {
      size_t e = src0 + (size_t)c * 2048 + (size_t)t * 8;
      fx4 v0 = *(const fx4*)&X[e];
      fx4 v1 = *(const fx4*)&X[e + 4];
      ux8 b;
      b[0] = f2bf(v0.x); b[1] = f2bf(v0.y); b[2] = f2bf(v0.z); b[3] = f2bf(v0.w);
      b[4] = f2bf(v1.x); b[5] = f2bf(v1.y); b[6] = f2bf(v1.z); b[7] = f2bf(v1.w);
      *(ux8*)&Xbf[dst0 + (size_t)c * 2048 + (size_t)t * 8] = b;
    }
    if (cb < 8) {
#pragma unroll
      for (int i = t; i < 2048; i += 256) rowssq[cb * 2048 + i] = 0.f;
    }
  }
}

// ---------------------------------------------------------------------------
// K1 (R8, proven): emb = Xbf @ Wt^T + ssq. 128x128 tile, BK=64, grid 512,
// DMA-dbuf, global-side XOR swizzle (0 conflicts measured).
// ---------------------------------------------------------------------------
__global__ __launch_bounds__(256) void k_gemm_embed(
    const unsigned short* __restrict__ Xbf, const unsigned short* __restrict__ Wt,
    unsigned short* __restrict__ emb, float* __restrict__ rowssq) {
  __shared__ unsigned short Ash[2][128 * 8 * 8];
  __shared__ unsigned short Bsh[2][128 * 8 * 8];

  int lid = blockIdx.x;
  int x = lid & 7;
  int s = lid >> 3;
  int m_blk = x * 16 + (s >> 2);
  int n_blk = s & 3;

  const unsigned short* Xrow = Xbf + (size_t)m_blk * 128 * KDIM;
  const unsigned short* Wrow = Wt + (size_t)n_blk * 128 * KDIM;

  int t = threadIdx.x;
  int lane = t & 63, w = t >> 6;
  int wm = w >> 1, wn = w & 1;
  int quad = lane >> 4, ml = lane & 15;

  fx4 acc[4][4];
#pragma unroll
  for (int i = 0; i < 4; ++i)
#pragma unroll
    for (int j = 0; j < 4; ++j) acc[i][j] = fx4{0.f, 0.f, 0.f, 0.f};

  auto stage = [&](int kt, int b) {
    int k0 = kt * 64;
#pragma unroll
    for (int c = 0; c < 4; ++c) {
      int ch = t + 256 * c;
      int m = ch >> 3;
      int kq = (ch & 7) ^ (m & 7);
      async_ld16(&Xrow[(size_t)m * KDIM + k0 + kq * 8],
                 &Ash[b][(w * 64 + 256 * c) * 8]);
    }
#pragma unroll
    for (int c = 0; c < 4; ++c) {
      int ch = t + 256 * c;
      int n = ch >> 3;
      int kq = (ch & 7) ^ (n & 7);
      async_ld16(&Wrow[(size_t)n * KDIM + k0 + kq * 8],
                 &Bsh[b][(w * 64 + 256 * c) * 8]);
    }
  };

  stage(0, 0);
  for (int kt = 0; kt < 16; ++kt) {
    int b = kt & 1;
    __syncthreads();
    if (kt < 15) stage(kt + 1, b ^ 1);
#pragma unroll
    for (int s2 = 0; s2 < 2; ++s2) {
      int kq = s2 * 4 + quad;
      sx8 af[4], bfr[4];
#pragma unroll
      for (int i = 0; i < 4; ++i) {
        int row = wm * 64 + i * 16 + ml;
        af[i] = *(const sx8*)&Ash[b][(row * 8 + (kq ^ (row & 7))) * 8];
      }
#pragma unroll
      for (int j = 0; j < 4; ++j) {
        int nrow = wn * 64 + j * 16 + ml;
        bfr[j] = *(const sx8*)&Bsh[b][(nrow * 8 + (kq ^ (nrow & 7))) * 8];
      }
#pragma unroll
      for (int i = 0; i < 4; ++i)
#pragma unroll
        for (int j = 0; j < 4; ++j)
          acc[i][j] = __builtin_amdgcn_mfma_f32_16x16x32_bf16(af[i], bfr[j], acc[i][j], 0, 0, 0);
    }
  }

  int grow = m_blk * 128 + wm * 64;
  int gcol = n_blk * 128 + wn * 64;
#pragma unroll
  for (int i = 0; i < 4; ++i) {
#pragma unroll
    for (int r = 0; r < 4; ++r) {
      int mrow = grow + i * 16 + quad * 4 + r;
      float p = 0.f;
#pragma unroll
      for (int j = 0; j < 4; ++j) {
        emb[(size_t)mrow * ED + gcol + j * 16 + ml] = f2bf(acc[i][j][r]);
        p += acc[i][j][r] * acc[i][j][r];
      }
#pragma unroll
      for (int off = 1; off < 16; off <<= 1) p += __shfl_xor(p, off, 16);
      if (ml == 0) atomicAdd(&rowssq[mrow], p);
    }
  }
}

// ---------------------------------------------------------------------------
// K2: cooperative TAIL — proto_partial + reduce + scores in one launch.
// 256 blocks x 256 (1/CU — admissible): the tail phases are cheap and
// latency-tolerant; fusing them removes 2 graph nodes + gaps (~25 us, R10
// calibration: ~12 us/launch). GEMM/prep stay separate (R10 showed fusing
// THOSE at 1 block/CU costs 150+ us of lost occupancy).
// ---------------------------------------------------------------------------
__global__ __launch_bounds__(256, 1) void k_tail(
    const unsigned short* __restrict__ emb, const float* __restrict__ rowssq,
    const int* __restrict__ labels, float* __restrict__ Ppart,
    unsigned short* __restrict__ Pbf, float* __restrict__ out) {
  __shared__ float Pl[NC * 64];  // 16 KB
  cg::grid_group grid = cg::this_grid();
  int lid = blockIdx.x, t = threadIdx.x;
  int lane = t & 63, w = t >> 6;

  // -- A: per-class partials. 32 chunks x 8 dim-slices, 256 rows/chunk,
  //       one lane-exclusive LDS atomic per row (2-way banks = free).
  {
    int chunk = lid >> 3, ds = lid & 7;
#pragma unroll
    for (int i = 0; i < 16; ++i) Pl[i * 256 + t] = 0.f;
    __syncthreads();
    int row0 = chunk * 256;
#pragma unroll 4
    for (int r = w; r < 256; r += 4) {
      int row = row0 + r;
      int lbl = labels[row];
      float scale = 1.0f / fmaxf(sqrtf(rowssq[row]), 1e-12f);
      float v = bf2f(emb[(size_t)row * ED + ds * 64 + lane]) * scale;
      atomicAdd(&Pl[lbl * 64 + lane], v);
    }
    __syncthreads();
    float* o = Ppart + (size_t)chunk * NC * ED + ds * 64;
#pragma unroll
    for (int i = 0; i < 16; ++i) {
      int idx = i * 256 + t;
      o[(size_t)(idx >> 6) * ED + (idx & 63)] = Pl[idx];
    }
  }
  grid.sync();

  // -- B: reduce 32 partials -> Pbf (bf16, MFMA B-fragment layout [kq][n][8])
  if (lid < 128) {
    int idx = lid * 256 + t;
    int kq = idx >> 9;
    int n = (idx >> 3) & 63;
    int j = idx & 7;
    int d = kq * 8 + j;
    float s = 0.f;
#pragma unroll 8
    for (int b = 0; b < 32; ++b) s += Ppart[(size_t)b * NC * ED + n * ED + d];
    Pbf[idx] = f2bf(s);
  }
  grid.sync();

  // -- C: scores + softmax. 2 waves x 16 queries per block.
  if (w < 2) {
    int quad = lane >> 4, ml = lane & 15;
    int qrow0 = lid * 32 + w * 16;
    const unsigned short* embQ = emb + (size_t)NS * ED;
    const float* ssqQ = rowssq + NS;

    fx4 acc[4];
#pragma unroll
    for (int i = 0; i < 4; ++i) acc[i] = fx4{0.f, 0.f, 0.f, 0.f};

#pragma unroll 4
    for (int ki = 0; ki < 16; ++ki) {
      sx8 a = *(const sx8*)&embQ[(size_t)(qrow0 + ml) * ED + ki * 32 + quad * 8];
#pragma unroll
      for (int nt = 0; nt < 4; ++nt) {
        sx8 b = *(const sx8*)&Pbf[((ki * 4 + quad) * 64 + nt * 16 + ml) * 8];
        acc[nt] = __builtin_amdgcn_mfma_f32_16x16x32_bf16(a, b, acc[nt], 0, 0, 0);
      }
    }

#pragma unroll
    for (int r = 0; r < 4; ++r) {
      int qq = qrow0 + quad * 4 + r;
      float scale = 1.0f / fmaxf(sqrtf(ssqQ[qq]), 1e-12f);
      float s[4];
#pragma unroll
      for (int nt = 0; nt < 4; ++nt) s[nt] = acc[nt][r] * scale;
      float m = fmaxf(fmaxf(s[0], s[1]), fmaxf(s[2], s[3]));
#pragma unroll
      for (int off = 1; off < 16; off <<= 1) m = fmaxf(m, __shfl_xor(m, off, 16));
      float e[4], ssum = 0.f;
#pragma unroll
      for (int nt = 0; nt < 4; ++nt) { e[nt] = __expf(s[nt] - m); ssum += e[nt]; }
#pragma unroll
      for (int off = 1; off < 16; off <<= 1) ssum += __shfl_xor(ssum, off, 16);
      float inv = 1.0f / ssum;
#pragma unroll
      for (int nt = 0; nt < 4; ++nt)
        out[(size_t)qq * NC + nt * 16 + ml] = e[nt] * inv;
    }
  }
}

// ===========================================================================
// Fallback tail (R8, proven) — used only if the cooperative launch fails.
// ===========================================================================
__global__ __launch_bounds__(256) void k_proto_partial(
    const unsigned short* __restrict__ embS, const float* __restrict__ rowssq,
    const int* __restrict__ labels, float* __restrict__ Ppart) {
  __shared__ float Pl[NC * 64];
  int t = threadIdx.x;
#pragma unroll
  for (int i = 0; i < 16; ++i) Pl[i * 256 + t] = 0.f;
  __syncthreads();

  int w = t >> 6, lane = t & 63;
  int ds = blockIdx.y;
  int row0 = blockIdx.x * (NS / PBLK);
#pragma unroll 4
  for (int r = w; r < NS / PBLK; r += 4) {
    int row = row0 + r;
    int lbl = labels[row];
    float scale = 1.0f / fmaxf(sqrtf(rowssq[row]), 1e-12f);
    float v = bf2f(embS[(size_t)row * ED + ds * 64 + lane]) * scale;
    atomicAdd(&Pl[lbl * 64 + lane], v);
  }
  __syncthreads();

  float* o = Ppart + (size_t)blockIdx.x * NC * ED + ds * 64;
#pragma unroll
  for (int i = 0; i < 16; ++i) {
    int idx = i * 256 + t;
    o[(size_t)(idx >> 6) * ED + (idx & 63)] = Pl[idx];
  }
}

__global__ __launch_bounds__(256) void k_proto_reduce(
    const float* __restrict__ Ppart, unsigned short* __restrict__ Pbf) {
  int idx = blockIdx.x * 256 + threadIdx.x;
  int kq = idx >> 9;
  int n = (idx >> 3) & 63;
  int j = idx & 7;
  int d = kq * 8 + j;
  float s = 0.f;
#pragma unroll 8
  for (int b = 0; b < PBLK; ++b) s += Ppart[(size_t)b * NC * ED + n * ED + d];
  Pbf[idx] = f2bf(s);
}

__global__ __launch_bounds__(64) void k_scores(
    const unsigned short* __restrict__ embQ, const float* __restrict__ ssqQ,
    const unsigned short* __restrict__ Pbf, float* __restrict__ out) {
  int lane = threadIdx.x;
  int quad = lane >> 4, ml = lane & 15;
  int qrow0 = blockIdx.x * 16;

  fx4 acc[4];
#pragma unroll
  for (int i = 0; i < 4; ++i) acc[i] = fx4{0.f, 0.f, 0.f, 0.f};

#pragma unroll 4
  for (int ki = 0; ki < 16; ++ki) {
    sx8 a = *(const sx8*)&embQ[(size_t)(qrow0 + ml) * ED + ki * 32 + quad * 8];
#pragma unroll
    for (int nt = 0; nt < 4; ++nt) {
      sx8 b = *(const sx8*)&Pbf[((ki * 4 + quad) * 64 + nt * 16 + ml) * 8];
      acc[nt] = __builtin_amdgcn_mfma_f32_16x16x32_bf16(a, b, acc[nt], 0, 0, 0);
    }
  }

#pragma unroll
  for (int r = 0; r < 4; ++r) {
    int qq = qrow0 + quad * 4 + r;
    float scale = 1.0f / fmaxf(sqrtf(ssqQ[qq]), 1e-12f);
    float s[4];
#pragma unroll
    for (int nt = 0; nt < 4; ++nt) s[nt] = acc[nt][r] * scale;
    float m = fmaxf(fmaxf(s[0], s[1]), fmaxf(s[2], s[3]));
#pragma unroll
    for (int off = 1; off < 16; off <<= 1) m = fmaxf(m, __shfl_xor(m, off, 16));
    float e[4], ssum = 0.f;
#pragma unroll
    for (int nt = 0; nt < 4; ++nt) { e[nt] = __expf(s[nt] - m); ssum += e[nt]; }
#pragma unroll
    for (int off = 1; off < 16; off <<= 1) ssum += __shfl_xor(ssum, off, 16);
    float inv = 1.0f / ssum;
#pragma unroll
    for (int nt = 0; nt < 4; ++nt)
      out[(size_t)qq * NC + nt * 16 + ml] = e[nt] * inv;
  }
}

// ---------------------------------------------------------------------------
extern "C" void kernel_launch(void* const* d_in, const int* in_sizes, int n_in,
                              void* d_out, int out_size, void* d_ws, size_t ws_size,
                              hipStream_t stream) {
  const float* Xs     = (const float*)d_in[0];
  const int*   labels = (const int*)d_in[1];
  const float* Xq     = (const float*)d_in[2];
  const float* W      = (const float*)d_in[3];
  float* out = (float*)d_out;

  char* ws = (char*)d_ws;
  size_t off = 0;
  unsigned short* Wt  = (unsigned short*)(ws + off); off += (size_t)ED * KDIM * 2;    // 1 MB
  unsigned short* Xbf = (unsigned short*)(ws + off); off += (size_t)NTOT * KDIM * 2;  // 33.5 MB
  unsigned short* emb = (unsigned short*)(ws + off); off += (size_t)NTOT * ED * 2;    // 16 MB
  float* rowssq = (float*)(ws + off); off += (size_t)NTOT * 4;                        // 64 KB
  float* Ppart  = (float*)(ws + off); off += (size_t)PBLK * NC * ED * 4;              // 8 MB
  unsigned short* Pbf = (unsigned short*)(ws + off); off += (size_t)NC * ED * 2;      // 64 KB

  k_prep<<<2560, 256, 0, stream>>>(W, Xs, Xq, Wt, Xbf, rowssq);
  k_gemm_embed<<<512, 256, 0, stream>>>(Xbf, Wt, emb, rowssq);

  const unsigned short* embC = emb;
  void* args[] = {(void*)&embC, (void*)&rowssq, (void*)&labels,
                  (void*)&Ppart, (void*)&Pbf, (void*)&out};
  hipError_t err = hipLaunchCooperativeKernel((const void*)k_tail, dim3(256),
                                              dim3(256), args, 0, stream);
  if (err != hipSuccess) {
    (void)hipGetLastError();  // clear sticky error, take the proven R8 tail
    k_proto_partial<<<dim3(PBLK, 8), 256, 0, stream>>>(emb, rowssq, labels, Ppart);
    k_proto_reduce<<<NC * ED / 256, 256, 0, stream>>>(Ppart, Pbf);
    k_scores<<<NQ / 16, 64, 0, stream>>>(emb + (size_t)NS * ED, rowssq + NS, Pbf, out);
  }
}